// Round 14
// baseline (294.131 us; speedup 1.0000x reference)
//
#include <hip/hip_runtime.h>
#include <hip/hip_bf16.h>

// SimpleMetaConvKALN: x (64,64,64,64) f32, w (32,80,3,3) f32 -> out (64,128,64,64) f32
// y = conv3x3(aug(x), w) per group; instance-norm per (b,oc); silu.
// K=64 (ones-block analytic via T[oc][ey][ex]).
// R12 structure (proven best): full weight table in LDS, K in 4 phases
// (silu/xn/P2/P3) from x-in-registers, single aug buffer, 2 barriers/phase.
// New: 2 tiles per block (weight staging amortized), group min/max reduce
// fused into conv prologue.  y transits conv->norm as bf16 scratch (ws-gated).

#define NB 64
#define NH 64
#define NW 64

typedef __attribute__((ext_vector_type(8)))  short bf16x8;
typedef __attribute__((ext_vector_type(8)))  unsigned short u16x8;
typedef __attribute__((ext_vector_type(16))) float f32x16;

__device__ __forceinline__ float silu(float v) {
    return v / (1.0f + __expf(-v));
}
__device__ __forceinline__ unsigned short tobf(float f) {   // native cvt (RNE)
    union { __hip_bfloat16 h; unsigned short u; } cv;
    cv.h = __float2bfloat16(f);
    return cv.u;
}

// ---- per-plane min/max (no atomics) ----
__global__ __launch_bounds__(256) void minmax_kernel(const float* __restrict__ x,
                                                     float* __restrict__ pmm) {
    int plane = blockIdx.x;          // b*64 + ch
    const float4* p = (const float4*)(x + (size_t)plane * 4096);
    int t = threadIdx.x;
    float mn = 3.4e38f, mx = -3.4e38f;
    #pragma unroll
    for (int k = 0; k < 4; ++k) {
        float4 v = p[t + k * 256];
        mn = fminf(mn, fminf(fminf(v.x, v.y), fminf(v.z, v.w)));
        mx = fmaxf(mx, fmaxf(fmaxf(v.x, v.y), fmaxf(v.z, v.w)));
    }
    #pragma unroll
    for (int off = 32; off; off >>= 1) {
        mn = fminf(mn, __shfl_xor(mn, off));
        mx = fmaxf(mx, __shfl_xor(mx, off));
    }
    __shared__ float smn[4], smx[4];
    int wid = t >> 6, lane = t & 63;
    if (lane == 0) { smn[wid] = mn; smx[wid] = mx; }
    __syncthreads();
    if (t == 0) {
        mn = fminf(fminf(smn[0], smn[1]), fminf(smn[2], smn[3]));
        mx = fmaxf(fmaxf(smx[0], smx[1]), fmaxf(smx[2], smx[3]));
        pmm[plane * 2]     = mn;
        pmm[plane * 2 + 1] = mx;
    }
}

// blk 0-71: repack w -> bf16 phase-major [p][tap][h][oc][8]
// blk 72: ones-channel analytic table T[oc][ey][ex]
__global__ __launch_bounds__(256) void repack_kernel(const float* __restrict__ w,
                                                     unsigned short* __restrict__ wpk,
                                                     float* __restrict__ Tt) {
    int blk = blockIdx.x;
    int t = threadIdx.x;
    if (blk < 72) {
        int idx = blk * 256 + t;             // < 18432 = 4*9*2*32*8
        int p   = idx / 4608;                // phase
        int r1  = idx - p * 4608;
        int tap = r1 / 512;
        int r2  = r1 - tap * 512;
        int h   = r2 >> 8;                   // k-half within phase
        int oc  = (r2 >> 3) & 31;
        int j   = r2 & 7;
        int k   = p * 16 + h * 8 + j;
        int orig = (k < 16) ? k : (k + 16);  // skip ones block (orig 16..31)
        wpk[idx] = tobf(w[oc * 720 + orig * 9 + tap]);
    } else {
        for (int i = t; i < 288; i += 256) {
            int oc = i / 9, ty = i - oc * 9;
            int ey = ty / 3, ex = ty - ey * 3;
            int ky0 = (ey == 0) ? 1 : 0, ky1 = (ey == 2) ? 1 : 2;
            int kx0 = (ex == 0) ? 1 : 0, kx1 = (ex == 2) ? 1 : 2;
            float s = 0.f;
            for (int c = 0; c < 16; ++c)
                for (int ky = ky0; ky <= ky1; ++ky)
                    for (int kx = kx0; kx <= kx1; ++kx)
                        s += w[oc * 720 + (16 + c) * 9 + ky * 3 + kx];
            Tt[i] = s;
        }
    }
}

__global__ __launch_bounds__(512, 6) void conv_mfma_kernel(const float* __restrict__ x,
                                                           const float* __restrict__ pmm,
                                                           const unsigned short* __restrict__ wpk,
                                                           const float* __restrict__ Tt,
                                                           float* __restrict__ out,
                                                           unsigned short* __restrict__ yscr) {
    __shared__ unsigned short wl[18432];    // [p][tap][h][oc][8]  36864 B (all phases)
    __shared__ unsigned short augp[5184];   // [h][pix 0..323][8]  10368 B
    __shared__ float Tl[288];               // 1152 B
    __shared__ float mmbc[2];               // xmin, xmax broadcast
    __shared__ float smn[8], smx[8];

    // XCD swizzle over 2048 blocks: each XCD gets a contiguous (b,g) range
    int flat = blockIdx.x;                       // 0..2047
    int f = ((flat & 7) << 8) | (flat >> 3);     // bijective
    int tp = f & 7;                              // tile-pair
    int bg = f >> 3;
    int b = bg & 63;
    int g = bg >> 6;

    const float* xg = x + ((size_t)b * 64 + g * 16) * 4096;
    int t = threadIdx.x;

    // ---- full weight table: global -> LDS once (2304 uint4) ----
    {
        const uint4* srcw = (const uint4*)wpk;
        uint4* dstw = (uint4*)wl;
        #pragma unroll
        for (int i = 0; i < 5; ++i) {
            int idx = t + i * 512;
            if (idx < 2304) dstw[idx] = srcw[idx];
        }
    }
    if (t < 288) Tl[t] = Tt[t];

    // ---- fused group min/max reduce over pmm (1024 planes of this g) ----
    {
        float mn = 3.4e38f, mx = -3.4e38f;
        #pragma unroll
        for (int j = 0; j < 2; ++j) {
            int p = t + j * 512;                 // 0..1023
            int bb = p >> 4, cc = p & 15;
            int plane = bb * 64 + g * 16 + cc;
            mn = fminf(mn, pmm[plane * 2]);
            mx = fmaxf(mx, pmm[plane * 2 + 1]);
        }
        #pragma unroll
        for (int off = 32; off; off >>= 1) {
            mn = fminf(mn, __shfl_xor(mn, off));
            mx = fmaxf(mx, __shfl_xor(mx, off));
        }
        int wid = t >> 6, lane = t & 63;
        if (lane == 0) { smn[wid] = mn; smx[wid] = mx; }
    }
    __syncthreads();
    if (t == 0) {
        float mn = smn[0], mx = smx[0];
        #pragma unroll
        for (int i = 1; i < 8; ++i) {
            mn = fminf(mn, smn[i]);
            mx = fmaxf(mx, smx[i]);
        }
        mmbc[0] = mn;
        mmbc[1] = mx;
    }
    __syncthreads();
    float xmin = mmbc[0];
    float inv = 2.0f / (mmbc[1] - xmin);

    int wv = t >> 6;
    int lane = t & 63;
    int lo = lane & 31, hi = lane >> 5;
    int py = 2 * wv + (lo >> 4), px = lo & 15;

    // ================= 2 tiles per block =================
    for (int tp2 = 0; tp2 < 2; ++tp2) {
        int tile = tp * 2 + tp2;                 // 0..15
        int th0 = (tile >> 2) * 16, tw0 = (tile & 3) * 16;

        // ---- load x halo tile into registers: 648 tasks = 324 px x 2 halves ----
        float r[2][8];
        bool okv[2];
        #pragma unroll
        for (int i = 0; i < 2; ++i) {
            okv[i] = false;
            int idx = t + i * 512;
            if (idx < 648) {
                int half = idx >= 324 ? 1 : 0;
                int pix = idx - half * 324;
                int ly = pix / 18, lx = pix - ly * 18;
                int gh = th0 + ly - 1, gw = tw0 + lx - 1;
                bool ok = (gh >= 0 && gh < NH && gw >= 0 && gw < NW);
                okv[i] = ok;
                const float* s = xg + (size_t)(half * 8) * 4096 + gh * 64 + gw;
                #pragma unroll
                for (int j = 0; j < 8; ++j)
                    r[i][j] = ok ? s[(size_t)j * 4096] : 0.f;
            }
        }

        f32x16 acc = {};

        // ---- 4 K-phases: 0=silu, 1=xn, 2=P2, 3=P3 ----
        #pragma unroll
        for (int p = 0; p < 4; ++p) {
            // stage this phase's transform (all b128 writes, reg->VALU->LDS)
            #pragma unroll
            for (int i = 0; i < 2; ++i) {
                int idx = t + i * 512;
                if (idx < 648) {
                    int half = idx >= 324 ? 1 : 0;
                    int pix = idx - half * 324;
                    bf16x8 v;
                    #pragma unroll
                    for (int j = 0; j < 8; ++j) {
                        float val = r[i][j];
                        float o;
                        if (p == 0) {
                            o = silu(val);               // silu(0)=0: OOB safe
                        } else {
                            float xn = (val - xmin) * inv - 1.f;
                            if (p == 1) o = xn;
                            else {
                                float x2 = xn * xn;
                                o = (p == 2) ? (1.5f * x2 - 0.5f)
                                             : ((2.5f * x2 - 1.5f) * xn);
                            }
                            o = okv[i] ? o : 0.f;
                        }
                        v[j] = (short)tobf(o);
                    }
                    *(bf16x8*)&augp[(half * 324 + pix) * 8] = v;
                }
            }
            __syncthreads();

            // 9 MFMAs: one per tap (K=16 = h0/h1 halves of this phase)
            #pragma unroll
            for (int tap = 0; tap < 9; ++tap) {
                const int ky = tap / 3, kx = tap % 3;
                const int hp = (py + ky) * 18 + (px + kx);
                bf16x8 Af = *(const bf16x8*)&wl[(((p * 9 + tap) * 2 + hi) * 32 + lo) * 8];
                bf16x8 Bf = *(const bf16x8*)&augp[(hi * 324 + hp) * 8];
                acc = __builtin_amdgcn_mfma_f32_32x32x16_bf16(Af, Bf, acc, 0, 0, 0);
            }
            __syncthreads();
        }

        // ---- epilogue: ones-term + stores (bf16 scratch if available) ----
        int h = th0 + py, wc = tw0 + px;
        int ey = (h == 0) ? 0 : ((h == NH - 1) ? 2 : 1);
        int ex = (wc == 0) ? 0 : ((wc == NW - 1) ? 2 : 1);
        int et = ey * 3 + ex;
        size_t obase = ((size_t)b * 128 + g * 32) * 4096 + (size_t)h * 64 + wc;
        if (yscr) {
            #pragma unroll
            for (int rr = 0; rr < 16; ++rr) {
                int oc = (rr & 3) + 8 * (rr >> 2) + 4 * hi;
                yscr[obase + (size_t)oc * 4096] = tobf(acc[rr] + Tl[oc * 9 + et]);
            }
        } else {
            #pragma unroll
            for (int rr = 0; rr < 16; ++rr) {
                int oc = (rr & 3) + 8 * (rr >> 2) + 4 * hi;
                out[obase + (size_t)oc * 4096] = acc[rr] + Tl[oc * 9 + et];
            }
        }
    }
}

// ---- norm from bf16 scratch: read 67MB, write 134MB ----
__global__ __launch_bounds__(256) void norm_bf16_kernel(const unsigned short* __restrict__ yscr,
                                                        float* __restrict__ out) {
    int plane = blockIdx.x;      // b*128 + ch
    const u16x8* p = (const u16x8*)(yscr + (size_t)plane * 4096);
    int t = threadIdx.x;
    float v[2][8];
    float s = 0.f, s2 = 0.f;
    #pragma unroll
    for (int k = 0; k < 2; ++k) {
        u16x8 u = p[t + k * 256];
        #pragma unroll
        for (int j = 0; j < 8; ++j) {
            float f = __uint_as_float((unsigned)u[j] << 16);
            v[k][j] = f;
            s += f;
            s2 += f * f;
        }
    }
    #pragma unroll
    for (int off = 32; off; off >>= 1) {
        s  += __shfl_xor(s, off);
        s2 += __shfl_xor(s2, off);
    }
    __shared__ float ss[4], ss2[4];
    int wid = t >> 6, lane = t & 63;
    if (lane == 0) { ss[wid] = s; ss2[wid] = s2; }
    __syncthreads();
    s  = ss[0] + ss[1] + ss[2] + ss[3];
    s2 = ss2[0] + ss2[1] + ss2[2] + ss2[3];
    float mean = s * (1.f / 4096.f);
    float var  = fmaxf(s2 * (1.f / 4096.f) - mean * mean, 0.f);
    float istd = rsqrtf(var + 1e-5f);
    float4* o = (float4*)(out + (size_t)plane * 4096);
    #pragma unroll
    for (int k = 0; k < 2; ++k) {
        float4 a, bq;
        a.x = silu((v[k][0] - mean) * istd);
        a.y = silu((v[k][1] - mean) * istd);
        a.z = silu((v[k][2] - mean) * istd);
        a.w = silu((v[k][3] - mean) * istd);
        bq.x = silu((v[k][4] - mean) * istd);
        bq.y = silu((v[k][5] - mean) * istd);
        bq.z = silu((v[k][6] - mean) * istd);
        bq.w = silu((v[k][7] - mean) * istd);
        o[(t + k * 256) * 2]     = a;
        o[(t + k * 256) * 2 + 1] = bq;
    }
}

// ---- fallback: in-place f32 norm ----
__global__ __launch_bounds__(256) void norm_kernel(float* __restrict__ out) {
    int plane = blockIdx.x;      // b*128 + ch
    float4* p = (float4*)(out + (size_t)plane * 4096);
    int t = threadIdx.x;
    float4 v[4];
    float s = 0.f, s2 = 0.f;
    #pragma unroll
    for (int k = 0; k < 4; ++k) {
        v[k] = p[t + k * 256];
        s  += v[k].x + v[k].y + v[k].z + v[k].w;
        s2 += v[k].x * v[k].x + v[k].y * v[k].y + v[k].z * v[k].z + v[k].w * v[k].w;
    }
    #pragma unroll
    for (int off = 32; off; off >>= 1) {
        s  += __shfl_xor(s, off);
        s2 += __shfl_xor(s2, off);
    }
    __shared__ float ss[4], ss2[4];
    int wid = t >> 6, lane = t & 63;
    if (lane == 0) { ss[wid] = s; ss2[wid] = s2; }
    __syncthreads();
    s  = ss[0] + ss[1] + ss[2] + ss[3];
    s2 = ss2[0] + ss2[1] + ss2[2] + ss2[3];
    float mean = s * (1.f / 4096.f);
    float var  = fmaxf(s2 * (1.f / 4096.f) - mean * mean, 0.f);
    float istd = rsqrtf(var + 1e-5f);
    #pragma unroll
    for (int k = 0; k < 4; ++k) {
        float4 o;
        o.x = (v[k].x - mean) * istd; o.x = silu(o.x);
        o.y = (v[k].y - mean) * istd; o.y = silu(o.y);
        o.z = (v[k].z - mean) * istd; o.z = silu(o.z);
        o.w = (v[k].w - mean) * istd; o.w = silu(o.w);
        p[t + k * 256] = o;
    }
}

extern "C" void kernel_launch(void* const* d_in, const int* in_sizes, int n_in,
                              void* d_out, int out_size, void* d_ws, size_t ws_size,
                              hipStream_t stream) {
    const float* x = (const float*)d_in[0];
    const float* w = (const float*)d_in[1];
    float* out = (float*)d_out;
    float* pmm = (float*)((char*)d_ws + 64);                          // 8192 floats
    unsigned short* wpk = (unsigned short*)((char*)d_ws + 64 + 32768);// 18432 bf16
    float* Tt = (float*)((char*)d_ws + 64 + 32768 + 36864);           // 288 floats

    const size_t YSCR_OFF = 131072;
    const size_t YSCR_BYTES = (size_t)64 * 128 * 4096 * 2;            // 67.1 MB
    unsigned short* yscr = (ws_size >= YSCR_OFF + YSCR_BYTES)
                         ? (unsigned short*)((char*)d_ws + YSCR_OFF) : nullptr;

    hipLaunchKernelGGL(minmax_kernel, dim3(NB * 64), dim3(256), 0, stream, x, pmm);
    hipLaunchKernelGGL(repack_kernel, dim3(73), dim3(256), 0, stream, w, wpk, Tt);
    hipLaunchKernelGGL(conv_mfma_kernel, dim3(2048), dim3(512), 0, stream, x, pmm, wpk, Tt, out, yscr);
    if (yscr)
        hipLaunchKernelGGL(norm_bf16_kernel, dim3(NB * 128), dim3(256), 0, stream, yscr, out);
    else
        hipLaunchKernelGGL(norm_kernel, dim3(NB * 128), dim3(256), 0, stream, out);
}

// Round 15
// 136.971 us; speedup vs baseline: 2.1474x; 2.1474x over previous
//
#include <hip/hip_runtime.h>
#include <hip/hip_bf16.h>

// SimpleMetaConvKALN: x (64,64,64,64) f32, w (32,80,3,3) f32 -> out (64,128,64,64) f32
// y = conv3x3(aug(x), w) per group; instance-norm per (b,oc); silu.
// K=64 (ones-block analytic via T[oc][ey][ex]).
// R12 structure + aug double-buffer: full weight table in LDS, K in 4 phases
// (silu/xn/P2/P3) from x-in-registers; stage(p+1) overlaps MFMA(p); 1 barrier
// per phase.  y transits conv->norm as bf16 scratch (ws-gated, f32 fallback).

#define NB 64
#define NH 64
#define NW 64

typedef __attribute__((ext_vector_type(8)))  short bf16x8;
typedef __attribute__((ext_vector_type(8)))  unsigned short u16x8;
typedef __attribute__((ext_vector_type(16))) float f32x16;

__device__ __forceinline__ float silu(float v) {
    return v / (1.0f + __expf(-v));
}
__device__ __forceinline__ unsigned short tobf(float f) {   // native cvt (RNE)
    union { __hip_bfloat16 h; unsigned short u; } cv;
    cv.h = __float2bfloat16(f);
    return cv.u;
}

// ---- per-plane min/max (no atomics) ----
__global__ __launch_bounds__(256) void minmax_kernel(const float* __restrict__ x,
                                                     float* __restrict__ pmm) {
    int plane = blockIdx.x;          // b*64 + ch
    const float4* p = (const float4*)(x + (size_t)plane * 4096);
    int t = threadIdx.x;
    float mn = 3.4e38f, mx = -3.4e38f;
    #pragma unroll
    for (int k = 0; k < 4; ++k) {
        float4 v = p[t + k * 256];
        mn = fminf(mn, fminf(fminf(v.x, v.y), fminf(v.z, v.w)));
        mx = fmaxf(mx, fmaxf(fmaxf(v.x, v.y), fmaxf(v.z, v.w)));
    }
    #pragma unroll
    for (int off = 32; off; off >>= 1) {
        mn = fminf(mn, __shfl_xor(mn, off));
        mx = fmaxf(mx, __shfl_xor(mx, off));
    }
    __shared__ float smn[4], smx[4];
    int wid = t >> 6, lane = t & 63;
    if (lane == 0) { smn[wid] = mn; smx[wid] = mx; }
    __syncthreads();
    if (t == 0) {
        mn = fminf(fminf(smn[0], smn[1]), fminf(smn[2], smn[3]));
        mx = fmaxf(fmaxf(smx[0], smx[1]), fmaxf(smx[2], smx[3]));
        pmm[plane * 2]     = mn;
        pmm[plane * 2 + 1] = mx;
    }
}

// blk 0-3: reduce pmm -> wsf[g]
// blk 4-75: repack w -> bf16 phase-major [p][tap][h][oc][8]
// blk 76: ones-channel analytic table T[oc][ey][ex]
__global__ __launch_bounds__(256) void reduce_repack_kernel(const float* __restrict__ pmm,
                                                            const float* __restrict__ w,
                                                            float* __restrict__ wsf,
                                                            unsigned short* __restrict__ wpk,
                                                            float* __restrict__ Tt) {
    int blk = blockIdx.x;
    int t = threadIdx.x;
    if (blk < 4) {
        int g = blk;
        float mn = 3.4e38f, mx = -3.4e38f;
        #pragma unroll
        for (int j = 0; j < 4; ++j) {
            int p = t + j * 256;             // 0..1023
            int b = p >> 4, c = p & 15;
            int plane = b * 64 + g * 16 + c;
            mn = fminf(mn, pmm[plane * 2]);
            mx = fmaxf(mx, pmm[plane * 2 + 1]);
        }
        #pragma unroll
        for (int off = 32; off; off >>= 1) {
            mn = fminf(mn, __shfl_xor(mn, off));
            mx = fmaxf(mx, __shfl_xor(mx, off));
        }
        __shared__ float smn[4], smx[4];
        int wid = t >> 6, lane = t & 63;
        if (lane == 0) { smn[wid] = mn; smx[wid] = mx; }
        __syncthreads();
        if (t == 0) {
            mn = fminf(fminf(smn[0], smn[1]), fminf(smn[2], smn[3]));
            mx = fmaxf(fmaxf(smx[0], smx[1]), fmaxf(smx[2], smx[3]));
            wsf[g * 2]     = mn;
            wsf[g * 2 + 1] = mx;
        }
    } else if (blk < 76) {
        int idx = (blk - 4) * 256 + t;       // < 18432 = 4*9*2*32*8
        int p   = idx / 4608;                // phase
        int r1  = idx - p * 4608;
        int tap = r1 / 512;
        int r2  = r1 - tap * 512;
        int h   = r2 >> 8;                   // k-half within phase
        int oc  = (r2 >> 3) & 31;
        int j   = r2 & 7;
        int k   = p * 16 + h * 8 + j;
        int orig = (k < 16) ? k : (k + 16);  // skip ones block (orig 16..31)
        wpk[idx] = tobf(w[oc * 720 + orig * 9 + tap]);
    } else {
        for (int i = t; i < 288; i += 256) {
            int oc = i / 9, ty = i - oc * 9;
            int ey = ty / 3, ex = ty - ey * 3;
            int ky0 = (ey == 0) ? 1 : 0, ky1 = (ey == 2) ? 1 : 2;
            int kx0 = (ex == 0) ? 1 : 0, kx1 = (ex == 2) ? 1 : 2;
            float s = 0.f;
            for (int c = 0; c < 16; ++c)
                for (int ky = ky0; ky <= ky1; ++ky)
                    for (int kx = kx0; kx <= kx1; ++kx)
                        s += w[oc * 720 + (16 + c) * 9 + ky * 3 + kx];
            Tt[i] = s;
        }
    }
}

__global__ __launch_bounds__(512, 4) void conv_mfma_kernel(const float* __restrict__ x,
                                                           const float* __restrict__ wsf,
                                                           const unsigned short* __restrict__ wpk,
                                                           const float* __restrict__ Tt,
                                                           float* __restrict__ out,
                                                           unsigned short* __restrict__ yscr) {
    __shared__ unsigned short wl[18432];      // [p][tap][h][oc][8]  36864 B
    __shared__ unsigned short aug2[2][5184];  // [buf][h][pix][8]    2x10368 B
    __shared__ float Tl[288];                 // 1152 B

    // XCD swizzle: consecutive work-chunks of 512 land on one XCD
    int flat = blockIdx.x;                       // 0..4095
    int f = ((flat & 7) << 9) | (flat >> 3);     // bijective
    int tile = f & 15;
    int bg = f >> 4;
    int b = bg & 63;
    int g = bg >> 6;
    int th0 = (tile >> 2) * 16, tw0 = (tile & 3) * 16;

    float xmin = wsf[g * 2];
    float xmax = wsf[g * 2 + 1];
    float inv = 2.0f / (xmax - xmin);

    const float* xg = x + ((size_t)b * 64 + g * 16) * 4096;
    int t = threadIdx.x;

    // ---- full weight table: global -> LDS once (2304 uint4) ----
    {
        const uint4* srcw = (const uint4*)wpk;
        uint4* dstw = (uint4*)wl;
        #pragma unroll
        for (int i = 0; i < 5; ++i) {
            int idx = t + i * 512;
            if (idx < 2304) dstw[idx] = srcw[idx];
        }
    }
    if (t < 288) Tl[t] = Tt[t];

    // ---- load x halo tile into registers: 648 tasks = 324 px x 2 ch-halves ----
    float r[2][8];
    bool okv[2];
    #pragma unroll
    for (int i = 0; i < 2; ++i) {
        okv[i] = false;
        int idx = t + i * 512;
        if (idx < 648) {
            int half = idx >= 324 ? 1 : 0;
            int pix = idx - half * 324;
            int ly = pix / 18, lx = pix - ly * 18;
            int gh = th0 + ly - 1, gw = tw0 + lx - 1;
            bool ok = (gh >= 0 && gh < NH && gw >= 0 && gw < NW);
            okv[i] = ok;
            const float* s = xg + (size_t)(half * 8) * 4096 + gh * 64 + gw;
            #pragma unroll
            for (int j = 0; j < 8; ++j)
                r[i][j] = ok ? s[(size_t)j * 4096] : 0.f;
        }
    }

    int wv = t >> 6;
    int lane = t & 63;
    int lo = lane & 31, hi = lane >> 5;
    int py = 2 * wv + (lo >> 4), px = lo & 15;

    // ---- stage helper: phase p into buf (all b128 writes, reg->VALU->LDS) ----
    auto stage = [&](int p, unsigned short* buf) {
        #pragma unroll
        for (int i = 0; i < 2; ++i) {
            int idx = t + i * 512;
            if (idx < 648) {
                int half = idx >= 324 ? 1 : 0;
                int pix = idx - half * 324;
                bf16x8 v;
                #pragma unroll
                for (int j = 0; j < 8; ++j) {
                    float val = r[i][j];
                    float o;
                    if (p == 0) {
                        o = silu(val);               // silu(0)=0: OOB safe
                    } else {
                        float xn = (val - xmin) * inv - 1.f;
                        if (p == 1) o = xn;
                        else {
                            float x2 = xn * xn;
                            o = (p == 2) ? (1.5f * x2 - 0.5f)
                                         : ((2.5f * x2 - 1.5f) * xn);
                        }
                        o = okv[i] ? o : 0.f;
                    }
                    v[j] = (short)tobf(o);
                }
                *(bf16x8*)&buf[(half * 324 + pix) * 8] = v;
            }
        }
    };

    stage(0, aug2[0]);
    __syncthreads();      // wl + Tl + aug2[0] all visible

    f32x16 acc = {};

    // ---- 4 K-phases: 0=silu, 1=xn, 2=P2, 3=P3 ; 1 barrier per phase ----
    #pragma unroll
    for (int p = 0; p < 4; ++p) {
        const int cb = p & 1, nb = cb ^ 1;

        // stage next phase into the other buffer (overlaps MFMAs below)
        if (p < 3) stage(p + 1, aug2[nb]);

        // 9 MFMAs: A from wl, B from aug2[cb]
        #pragma unroll
        for (int tap = 0; tap < 9; ++tap) {
            const int ky = tap / 3, kx = tap % 3;
            const int hp = (py + ky) * 18 + (px + kx);
            bf16x8 Af = *(const bf16x8*)&wl[(((p * 9 + tap) * 2 + hi) * 32 + lo) * 8];
            bf16x8 Bf = *(const bf16x8*)&aug2[cb][(hi * 324 + hp) * 8];
            acc = __builtin_amdgcn_mfma_f32_32x32x16_bf16(Af, Bf, acc, 0, 0, 0);
        }

        // one barrier: my nb-writes visible to all; everyone done reading cb
        __syncthreads();
    }

    // ---- epilogue: ones-term + stores (bf16 scratch if available) ----
    int h = th0 + py, wc = tw0 + px;
    int ey = (h == 0) ? 0 : ((h == NH - 1) ? 2 : 1);
    int ex = (wc == 0) ? 0 : ((wc == NW - 1) ? 2 : 1);
    int et = ey * 3 + ex;
    size_t obase = ((size_t)b * 128 + g * 32) * 4096 + (size_t)h * 64 + wc;
    if (yscr) {
        #pragma unroll
        for (int rr = 0; rr < 16; ++rr) {
            int oc = (rr & 3) + 8 * (rr >> 2) + 4 * hi;
            yscr[obase + (size_t)oc * 4096] = tobf(acc[rr] + Tl[oc * 9 + et]);
        }
    } else {
        #pragma unroll
        for (int rr = 0; rr < 16; ++rr) {
            int oc = (rr & 3) + 8 * (rr >> 2) + 4 * hi;
            out[obase + (size_t)oc * 4096] = acc[rr] + Tl[oc * 9 + et];
        }
    }
}

// ---- norm from bf16 scratch: read 67MB, write 134MB ----
__global__ __launch_bounds__(256) void norm_bf16_kernel(const unsigned short* __restrict__ yscr,
                                                        float* __restrict__ out) {
    int plane = blockIdx.x;      // b*128 + ch
    const u16x8* p = (const u16x8*)(yscr + (size_t)plane * 4096);
    int t = threadIdx.x;
    float v[2][8];
    float s = 0.f, s2 = 0.f;
    #pragma unroll
    for (int k = 0; k < 2; ++k) {
        u16x8 u = p[t + k * 256];
        #pragma unroll
        for (int j = 0; j < 8; ++j) {
            float f = __uint_as_float((unsigned)u[j] << 16);
            v[k][j] = f;
            s += f;
            s2 += f * f;
        }
    }
    #pragma unroll
    for (int off = 32; off; off >>= 1) {
        s  += __shfl_xor(s, off);
        s2 += __shfl_xor(s2, off);
    }
    __shared__ float ss[4], ss2[4];
    int wid = t >> 6, lane = t & 63;
    if (lane == 0) { ss[wid] = s; ss2[wid] = s2; }
    __syncthreads();
    s  = ss[0] + ss[1] + ss[2] + ss[3];
    s2 = ss2[0] + ss2[1] + ss2[2] + ss2[3];
    float mean = s * (1.f / 4096.f);
    float var  = fmaxf(s2 * (1.f / 4096.f) - mean * mean, 0.f);
    float istd = rsqrtf(var + 1e-5f);
    float4* o = (float4*)(out + (size_t)plane * 4096);
    #pragma unroll
    for (int k = 0; k < 2; ++k) {
        float4 a, bq;
        a.x = silu((v[k][0] - mean) * istd);
        a.y = silu((v[k][1] - mean) * istd);
        a.z = silu((v[k][2] - mean) * istd);
        a.w = silu((v[k][3] - mean) * istd);
        bq.x = silu((v[k][4] - mean) * istd);
        bq.y = silu((v[k][5] - mean) * istd);
        bq.z = silu((v[k][6] - mean) * istd);
        bq.w = silu((v[k][7] - mean) * istd);
        o[(t + k * 256) * 2]     = a;
        o[(t + k * 256) * 2 + 1] = bq;
    }
}

// ---- fallback: in-place f32 norm ----
__global__ __launch_bounds__(256) void norm_kernel(float* __restrict__ out) {
    int plane = blockIdx.x;      // b*128 + ch
    float4* p = (float4*)(out + (size_t)plane * 4096);
    int t = threadIdx.x;
    float4 v[4];
    float s = 0.f, s2 = 0.f;
    #pragma unroll
    for (int k = 0; k < 4; ++k) {
        v[k] = p[t + k * 256];
        s  += v[k].x + v[k].y + v[k].z + v[k].w;
        s2 += v[k].x * v[k].x + v[k].y * v[k].y + v[k].z * v[k].z + v[k].w * v[k].w;
    }
    #pragma unroll
    for (int off = 32; off; off >>= 1) {
        s  += __shfl_xor(s, off);
        s2 += __shfl_xor(s2, off);
    }
    __shared__ float ss[4], ss2[4];
    int wid = t >> 6, lane = t & 63;
    if (lane == 0) { ss[wid] = s; ss2[wid] = s2; }
    __syncthreads();
    s  = ss[0] + ss[1] + ss[2] + ss[3];
    s2 = ss2[0] + ss2[1] + ss2[2] + ss2[3];
    float mean = s * (1.f / 4096.f);
    float var  = fmaxf(s2 * (1.f / 4096.f) - mean * mean, 0.f);
    float istd = rsqrtf(var + 1e-5f);
    #pragma unroll
    for (int k = 0; k < 4; ++k) {
        float4 o;
        o.x = (v[k].x - mean) * istd; o.x = silu(o.x);
        o.y = (v[k].y - mean) * istd; o.y = silu(o.y);
        o.z = (v[k].z - mean) * istd; o.z = silu(o.z);
        o.w = (v[k].w - mean) * istd; o.w = silu(o.w);
        p[t + k * 256] = o;
    }
}

extern "C" void kernel_launch(void* const* d_in, const int* in_sizes, int n_in,
                              void* d_out, int out_size, void* d_ws, size_t ws_size,
                              hipStream_t stream) {
    const float* x = (const float*)d_in[0];
    const float* w = (const float*)d_in[1];
    float* out = (float*)d_out;
    float* wsf = (float*)d_ws;                                        // 8 floats
    float* pmm = (float*)((char*)d_ws + 64);                          // 8192 floats
    unsigned short* wpk = (unsigned short*)((char*)d_ws + 64 + 32768);// 18432 bf16
    float* Tt = (float*)((char*)d_ws + 64 + 32768 + 36864);           // 288 floats

    const size_t YSCR_OFF = 131072;
    const size_t YSCR_BYTES = (size_t)64 * 128 * 4096 * 2;            // 67.1 MB
    unsigned short* yscr = (ws_size >= YSCR_OFF + YSCR_BYTES)
                         ? (unsigned short*)((char*)d_ws + YSCR_OFF) : nullptr;

    hipLaunchKernelGGL(minmax_kernel, dim3(NB * 64), dim3(256), 0, stream, x, pmm);
    hipLaunchKernelGGL(reduce_repack_kernel, dim3(77), dim3(256), 0, stream, pmm, w, wsf, wpk, Tt);
    hipLaunchKernelGGL(conv_mfma_kernel, dim3(4096), dim3(512), 0, stream, x, wsf, wpk, Tt, out, yscr);
    if (yscr)
        hipLaunchKernelGGL(norm_bf16_kernel, dim3(NB * 128), dim3(256), 0, stream, yscr, out);
    else
        hipLaunchKernelGGL(norm_kernel, dim3(NB * 128), dim3(256), 0, stream, out);
}

// Round 16
// 129.445 us; speedup vs baseline: 2.2722x; 1.0581x over previous
//
#include <hip/hip_runtime.h>
#include <hip/hip_bf16.h>

// SimpleMetaConvKALN: x (64,64,64,64) f32, w (32,80,3,3) f32 -> out (64,128,64,64) f32
// y = conv3x3(aug(x), w) per group; instance-norm per (b,oc); silu.
// K=64 (ones-block analytic via T[oc][ey][ex]).
// R12 phase structure; block covers 16x32 region (2 tiles), each wave holds
// TWO accumulators (left/right) reusing the A-frag: 1 A-read + 2 B-reads per
// 2 MFMAs (-25% LDS reads).  Weight table in LDS once per block (grid 2048).
// y transits conv->norm as bf16 scratch (ws-gated, f32 fallback).

#define NB 64
#define NH 64
#define NW 64

typedef __attribute__((ext_vector_type(8)))  short bf16x8;
typedef __attribute__((ext_vector_type(8)))  unsigned short u16x8;
typedef __attribute__((ext_vector_type(16))) float f32x16;

__device__ __forceinline__ float silu(float v) {
    return v / (1.0f + __expf(-v));
}
__device__ __forceinline__ unsigned short tobf(float f) {   // native cvt (RNE)
    union { __hip_bfloat16 h; unsigned short u; } cv;
    cv.h = __float2bfloat16(f);
    return cv.u;
}

// ---- per-plane min/max (no atomics) ----
__global__ __launch_bounds__(256) void minmax_kernel(const float* __restrict__ x,
                                                     float* __restrict__ pmm) {
    int plane = blockIdx.x;          // b*64 + ch
    const float4* p = (const float4*)(x + (size_t)plane * 4096);
    int t = threadIdx.x;
    float mn = 3.4e38f, mx = -3.4e38f;
    #pragma unroll
    for (int k = 0; k < 4; ++k) {
        float4 v = p[t + k * 256];
        mn = fminf(mn, fminf(fminf(v.x, v.y), fminf(v.z, v.w)));
        mx = fmaxf(mx, fmaxf(fmaxf(v.x, v.y), fmaxf(v.z, v.w)));
    }
    #pragma unroll
    for (int off = 32; off; off >>= 1) {
        mn = fminf(mn, __shfl_xor(mn, off));
        mx = fmaxf(mx, __shfl_xor(mx, off));
    }
    __shared__ float smn[4], smx[4];
    int wid = t >> 6, lane = t & 63;
    if (lane == 0) { smn[wid] = mn; smx[wid] = mx; }
    __syncthreads();
    if (t == 0) {
        mn = fminf(fminf(smn[0], smn[1]), fminf(smn[2], smn[3]));
        mx = fmaxf(fmaxf(smx[0], smx[1]), fmaxf(smx[2], smx[3]));
        pmm[plane * 2]     = mn;
        pmm[plane * 2 + 1] = mx;
    }
}

// blk 0-3: reduce pmm -> wsf[g]
// blk 4-75: repack w -> bf16 phase-major [p][tap][h][oc][8]
// blk 76: ones-channel analytic table T[oc][ey][ex]
__global__ __launch_bounds__(256) void reduce_repack_kernel(const float* __restrict__ pmm,
                                                            const float* __restrict__ w,
                                                            float* __restrict__ wsf,
                                                            unsigned short* __restrict__ wpk,
                                                            float* __restrict__ Tt) {
    int blk = blockIdx.x;
    int t = threadIdx.x;
    if (blk < 4) {
        int g = blk;
        float mn = 3.4e38f, mx = -3.4e38f;
        #pragma unroll
        for (int j = 0; j < 4; ++j) {
            int p = t + j * 256;             // 0..1023
            int b = p >> 4, c = p & 15;
            int plane = b * 64 + g * 16 + c;
            mn = fminf(mn, pmm[plane * 2]);
            mx = fmaxf(mx, pmm[plane * 2 + 1]);
        }
        #pragma unroll
        for (int off = 32; off; off >>= 1) {
            mn = fminf(mn, __shfl_xor(mn, off));
            mx = fmaxf(mx, __shfl_xor(mx, off));
        }
        __shared__ float smn[4], smx[4];
        int wid = t >> 6, lane = t & 63;
        if (lane == 0) { smn[wid] = mn; smx[wid] = mx; }
        __syncthreads();
        if (t == 0) {
            mn = fminf(fminf(smn[0], smn[1]), fminf(smn[2], smn[3]));
            mx = fmaxf(fmaxf(smx[0], smx[1]), fmaxf(smx[2], smx[3]));
            wsf[g * 2]     = mn;
            wsf[g * 2 + 1] = mx;
        }
    } else if (blk < 76) {
        int idx = (blk - 4) * 256 + t;       // < 18432 = 4*9*2*32*8
        int p   = idx / 4608;                // phase
        int r1  = idx - p * 4608;
        int tap = r1 / 512;
        int r2  = r1 - tap * 512;
        int h   = r2 >> 8;                   // k-half within phase
        int oc  = (r2 >> 3) & 31;
        int j   = r2 & 7;
        int k   = p * 16 + h * 8 + j;
        int orig = (k < 16) ? k : (k + 16);  // skip ones block (orig 16..31)
        wpk[idx] = tobf(w[oc * 720 + orig * 9 + tap]);
    } else {
        for (int i = t; i < 288; i += 256) {
            int oc = i / 9, ty = i - oc * 9;
            int ey = ty / 3, ex = ty - ey * 3;
            int ky0 = (ey == 0) ? 1 : 0, ky1 = (ey == 2) ? 1 : 2;
            int kx0 = (ex == 0) ? 1 : 0, kx1 = (ex == 2) ? 1 : 2;
            float s = 0.f;
            for (int c = 0; c < 16; ++c)
                for (int ky = ky0; ky <= ky1; ++ky)
                    for (int kx = kx0; kx <= kx1; ++kx)
                        s += w[oc * 720 + (16 + c) * 9 + ky * 3 + kx];
            Tt[i] = s;
        }
    }
}

__global__ __launch_bounds__(512, 4) void conv_mfma_kernel(const float* __restrict__ x,
                                                           const float* __restrict__ wsf,
                                                           const unsigned short* __restrict__ wpk,
                                                           const float* __restrict__ Tt,
                                                           float* __restrict__ out,
                                                           unsigned short* __restrict__ yscr) {
    __shared__ unsigned short wl[18432];    // [p][tap][h][oc][8]  36864 B
    __shared__ unsigned short augp[9792];   // [h][pix 0..611][8]  19584 B (18x34 halo)
    __shared__ float Tl[288];               // 1152 B

    // XCD swizzle over 2048 blocks
    int flat = blockIdx.x;                       // 0..2047
    int f = ((flat & 7) << 8) | (flat >> 3);     // bijective
    int q = f & 7;                               // region: 4x2 of 16x32
    int bg = f >> 3;
    int b = bg & 63;
    int g = bg >> 6;
    int th0 = (q >> 1) * 16, tw0 = (q & 1) * 32;

    float xmin = wsf[g * 2];
    float xmax = wsf[g * 2 + 1];
    float inv = 2.0f / (xmax - xmin);

    const float* xg = x + ((size_t)b * 64 + g * 16) * 4096;
    int t = threadIdx.x;

    // ---- full weight table: global -> LDS once (2304 uint4) ----
    {
        const uint4* srcw = (const uint4*)wpk;
        uint4* dstw = (uint4*)wl;
        #pragma unroll
        for (int i = 0; i < 5; ++i) {
            int idx = t + i * 512;
            if (idx < 2304) dstw[idx] = srcw[idx];
        }
    }
    if (t < 288) Tl[t] = Tt[t];

    // ---- x halo region into registers: 1224 tasks = 612 px x 2 ch-halves ----
    float r[3][8];
    bool okv[3];
    #pragma unroll
    for (int i = 0; i < 3; ++i) {
        okv[i] = false;
        int idx = t + i * 512;
        if (idx < 1224) {
            int half = idx >= 612 ? 1 : 0;
            int pix = idx - half * 612;
            int ly = pix / 34, lx = pix - ly * 34;
            int gh = th0 + ly - 1, gw = tw0 + lx - 1;
            bool ok = (gh >= 0 && gh < NH && gw >= 0 && gw < NW);
            okv[i] = ok;
            const float* s = xg + (size_t)(half * 8) * 4096 + gh * 64 + gw;
            #pragma unroll
            for (int j = 0; j < 8; ++j)
                r[i][j] = ok ? s[(size_t)j * 4096] : 0.f;
        }
    }

    int wv = t >> 6;
    int lane = t & 63;
    int lo = lane & 31, hi = lane >> 5;
    int py = 2 * wv + (lo >> 4), px = lo & 15;

    f32x16 acc0 = {}, acc1 = {};   // left (cols px), right (cols px+16)

    // ---- 4 K-phases: 0=silu, 1=xn, 2=P2, 3=P3 ----
    #pragma unroll
    for (int p = 0; p < 4; ++p) {
        // stage this phase's transform (all b128 writes, reg->VALU->LDS)
        #pragma unroll
        for (int i = 0; i < 3; ++i) {
            int idx = t + i * 512;
            if (idx < 1224) {
                int half = idx >= 612 ? 1 : 0;
                int pix = idx - half * 612;
                bf16x8 v;
                #pragma unroll
                for (int j = 0; j < 8; ++j) {
                    float val = r[i][j];
                    float o;
                    if (p == 0) {
                        o = silu(val);               // silu(0)=0: OOB safe
                    } else {
                        float xn = (val - xmin) * inv - 1.f;
                        if (p == 1) o = xn;
                        else {
                            float x2 = xn * xn;
                            o = (p == 2) ? (1.5f * x2 - 0.5f)
                                         : ((2.5f * x2 - 1.5f) * xn);
                        }
                        o = okv[i] ? o : 0.f;
                    }
                    v[j] = (short)tobf(o);
                }
                *(bf16x8*)&augp[(half * 612 + pix) * 8] = v;
            }
        }
        __syncthreads();

        // 9 taps: 1 A-read + 2 B-reads -> 2 MFMAs (independent acc chains)
        #pragma unroll
        for (int tap = 0; tap < 9; ++tap) {
            const int ky = tap / 3, kx = tap % 3;
            const int hp = (py + ky) * 34 + (px + kx);
            bf16x8 Af = *(const bf16x8*)&wl[(((p * 9 + tap) * 2 + hi) * 32 + lo) * 8];
            bf16x8 Bf0 = *(const bf16x8*)&augp[(hi * 612 + hp) * 8];
            bf16x8 Bf1 = *(const bf16x8*)&augp[(hi * 612 + hp + 16) * 8];
            acc0 = __builtin_amdgcn_mfma_f32_32x32x16_bf16(Af, Bf0, acc0, 0, 0, 0);
            acc1 = __builtin_amdgcn_mfma_f32_32x32x16_bf16(Af, Bf1, acc1, 0, 0, 0);
        }
        __syncthreads();
    }

    // ---- epilogue: ones-term + stores (bf16 scratch if available) ----
    int h = th0 + py;
    int ey = (h == 0) ? 0 : ((h == NH - 1) ? 2 : 1);
    size_t gbase = ((size_t)b * 128 + g * 32) * 4096 + (size_t)h * 64;

    int wc0 = tw0 + px;
    int ex0 = (wc0 == 0) ? 0 : ((wc0 == NW - 1) ? 2 : 1);
    int et0 = ey * 3 + ex0;
    int wc1 = tw0 + 16 + px;
    int ex1 = (wc1 == 0) ? 0 : ((wc1 == NW - 1) ? 2 : 1);
    int et1 = ey * 3 + ex1;

    if (yscr) {
        #pragma unroll
        for (int rr = 0; rr < 16; ++rr) {
            int oc = (rr & 3) + 8 * (rr >> 2) + 4 * hi;
            size_t o = gbase + (size_t)oc * 4096;
            yscr[o + wc0] = tobf(acc0[rr] + Tl[oc * 9 + et0]);
            yscr[o + wc1] = tobf(acc1[rr] + Tl[oc * 9 + et1]);
        }
    } else {
        #pragma unroll
        for (int rr = 0; rr < 16; ++rr) {
            int oc = (rr & 3) + 8 * (rr >> 2) + 4 * hi;
            size_t o = gbase + (size_t)oc * 4096;
            out[o + wc0] = acc0[rr] + Tl[oc * 9 + et0];
            out[o + wc1] = acc1[rr] + Tl[oc * 9 + et1];
        }
    }
}

// ---- norm from bf16 scratch: read 67MB, write 134MB ----
__global__ __launch_bounds__(256) void norm_bf16_kernel(const unsigned short* __restrict__ yscr,
                                                        float* __restrict__ out) {
    int plane = blockIdx.x;      // b*128 + ch
    const u16x8* p = (const u16x8*)(yscr + (size_t)plane * 4096);
    int t = threadIdx.x;
    float v[2][8];
    float s = 0.f, s2 = 0.f;
    #pragma unroll
    for (int k = 0; k < 2; ++k) {
        u16x8 u = p[t + k * 256];
        #pragma unroll
        for (int j = 0; j < 8; ++j) {
            float f = __uint_as_float((unsigned)u[j] << 16);
            v[k][j] = f;
            s += f;
            s2 += f * f;
        }
    }
    #pragma unroll
    for (int off = 32; off; off >>= 1) {
        s  += __shfl_xor(s, off);
        s2 += __shfl_xor(s2, off);
    }
    __shared__ float ss[4], ss2[4];
    int wid = t >> 6, lane = t & 63;
    if (lane == 0) { ss[wid] = s; ss2[wid] = s2; }
    __syncthreads();
    s  = ss[0] + ss[1] + ss[2] + ss[3];
    s2 = ss2[0] + ss2[1] + ss2[2] + ss2[3];
    float mean = s * (1.f / 4096.f);
    float var  = fmaxf(s2 * (1.f / 4096.f) - mean * mean, 0.f);
    float istd = rsqrtf(var + 1e-5f);
    float4* o = (float4*)(out + (size_t)plane * 4096);
    #pragma unroll
    for (int k = 0; k < 2; ++k) {
        float4 a, bq;
        a.x = silu((v[k][0] - mean) * istd);
        a.y = silu((v[k][1] - mean) * istd);
        a.z = silu((v[k][2] - mean) * istd);
        a.w = silu((v[k][3] - mean) * istd);
        bq.x = silu((v[k][4] - mean) * istd);
        bq.y = silu((v[k][5] - mean) * istd);
        bq.z = silu((v[k][6] - mean) * istd);
        bq.w = silu((v[k][7] - mean) * istd);
        o[(t + k * 256) * 2]     = a;
        o[(t + k * 256) * 2 + 1] = bq;
    }
}

// ---- fallback: in-place f32 norm ----
__global__ __launch_bounds__(256) void norm_kernel(float* __restrict__ out) {
    int plane = blockIdx.x;      // b*128 + ch
    float4* p = (float4*)(out + (size_t)plane * 4096);
    int t = threadIdx.x;
    float4 v[4];
    float s = 0.f, s2 = 0.f;
    #pragma unroll
    for (int k = 0; k < 4; ++k) {
        v[k] = p[t + k * 256];
        s  += v[k].x + v[k].y + v[k].z + v[k].w;
        s2 += v[k].x * v[k].x + v[k].y * v[k].y + v[k].z * v[k].z + v[k].w * v[k].w;
    }
    #pragma unroll
    for (int off = 32; off; off >>= 1) {
        s  += __shfl_xor(s, off);
        s2 += __shfl_xor(s2, off);
    }
    __shared__ float ss[4], ss2[4];
    int wid = t >> 6, lane = t & 63;
    if (lane == 0) { ss[wid] = s; ss2[wid] = s2; }
    __syncthreads();
    s  = ss[0] + ss[1] + ss[2] + ss[3];
    s2 = ss2[0] + ss2[1] + ss2[2] + ss2[3];
    float mean = s * (1.f / 4096.f);
    float var  = fmaxf(s2 * (1.f / 4096.f) - mean * mean, 0.f);
    float istd = rsqrtf(var + 1e-5f);
    #pragma unroll
    for (int k = 0; k < 4; ++k) {
        float4 o;
        o.x = (v[k].x - mean) * istd; o.x = silu(o.x);
        o.y = (v[k].y - mean) * istd; o.y = silu(o.y);
        o.z = (v[k].z - mean) * istd; o.z = silu(o.z);
        o.w = (v[k].w - mean) * istd; o.w = silu(o.w);
        p[t + k * 256] = o;
    }
}

extern "C" void kernel_launch(void* const* d_in, const int* in_sizes, int n_in,
                              void* d_out, int out_size, void* d_ws, size_t ws_size,
                              hipStream_t stream) {
    const float* x = (const float*)d_in[0];
    const float* w = (const float*)d_in[1];
    float* out = (float*)d_out;
    float* wsf = (float*)d_ws;                                        // 8 floats
    float* pmm = (float*)((char*)d_ws + 64);                          // 8192 floats
    unsigned short* wpk = (unsigned short*)((char*)d_ws + 64 + 32768);// 18432 bf16
    float* Tt = (float*)((char*)d_ws + 64 + 32768 + 36864);           // 288 floats

    const size_t YSCR_OFF = 131072;
    const size_t YSCR_BYTES = (size_t)64 * 128 * 4096 * 2;            // 67.1 MB
    unsigned short* yscr = (ws_size >= YSCR_OFF + YSCR_BYTES)
                         ? (unsigned short*)((char*)d_ws + YSCR_OFF) : nullptr;

    hipLaunchKernelGGL(minmax_kernel, dim3(NB * 64), dim3(256), 0, stream, x, pmm);
    hipLaunchKernelGGL(reduce_repack_kernel, dim3(77), dim3(256), 0, stream, pmm, w, wsf, wpk, Tt);
    hipLaunchKernelGGL(conv_mfma_kernel, dim3(2048), dim3(512), 0, stream, x, wsf, wpk, Tt, out, yscr);
    if (yscr)
        hipLaunchKernelGGL(norm_bf16_kernel, dim3(NB * 128), dim3(256), 0, stream, yscr, out);
    else
        hipLaunchKernelGGL(norm_kernel, dim3(NB * 128), dim3(256), 0, stream, out);
}